// Round 7
// baseline (141.152 us; speedup 1.0000x reference)
//
#include <hip/hip_runtime.h>

// Problem constants
#define NPATCH 196
#define M_ROWS 12544          // 64*196
#define KDIM 768              // 3*16*16
#define DDIM 384              // EMBED
#define HW (224*224)

typedef __attribute__((ext_vector_type(8))) short s16x8;
typedef __attribute__((ext_vector_type(4))) float f32x4;
typedef __attribute__((ext_vector_type(4))) unsigned short u16x4;

__device__ __forceinline__ unsigned short f2bf(float f) {
    unsigned int u = __float_as_uint(f);
    u += 0x7fff + ((u >> 16) & 1);   // round-to-nearest-even
    return (unsigned short)(u >> 16);
}

// ------- kernel 1: fused im2col(bf16) + patch entropy + weight cast ----------
// blocks [0,3136): one wave per patch -> bf16 A row + grayscale histogram.
// blocks [3136,3424): weight fp32->bf16 cast (384x768 row-major = B^T).
__global__ __launch_bounds__(256) void patch_kernel(const float* __restrict__ img,
                                                    const float* __restrict__ w,
                                                    unsigned short* __restrict__ A,
                                                    unsigned short* __restrict__ W,
                                                    float* __restrict__ ent) {
    if (blockIdx.x >= 3136) {                 // ---- weight cast part ----
        int t = (blockIdx.x - 3136) * 256 + threadIdx.x;   // 73728 float4s
        float4 v = ((const float4*)w)[t];
        u16x4 o = { f2bf(v.x), f2bf(v.y), f2bf(v.z), f2bf(v.w) };
        *(u16x4*)(W + t * 4) = o;
        return;
    }
    __shared__ int hist[4][32];
    const int lane = threadIdx.x & 63;
    const int wave = threadIdx.x >> 6;
    const int p = blockIdx.x * 4 + wave;      // 0..12543 == A row index
    const int b = p / NPATCH;
    const int n = p - b * NPATCH;
    const int ph = n / 14, pw = n - ph * 14;

    if (lane < 32) hist[wave][lane] = 0;
    __syncthreads();

    const int r = lane >> 2;                  // pixel row in patch 0..15
    const int cc = (lane & 3) * 4;            // pixel col 0,4,8,12
    const float* base = img + (size_t)b * (3 * HW) + (ph * 16 + r) * 224 + pw * 16 + cc;

    float4 v0 = *(const float4*)(base);
    float4 v1 = *(const float4*)(base + HW);
    float4 v2 = *(const float4*)(base + 2 * HW);

    unsigned short* arow = A + (size_t)p * KDIM;
    u16x4 o0 = { f2bf(v0.x), f2bf(v0.y), f2bf(v0.z), f2bf(v0.w) };
    u16x4 o1 = { f2bf(v1.x), f2bf(v1.y), f2bf(v1.z), f2bf(v1.w) };
    u16x4 o2 = { f2bf(v2.x), f2bf(v2.y), f2bf(v2.z), f2bf(v2.w) };
    *(u16x4*)(arow + 0 * 256 + lane * 4) = o0;
    *(u16x4*)(arow + 1 * 256 + lane * 4) = o1;
    *(u16x4*)(arow + 2 * 256 + lane * 4) = o2;

    float g[4] = { (v0.x + v1.x + v2.x) * (1.0f / 3.0f),
                   (v0.y + v1.y + v2.y) * (1.0f / 3.0f),
                   (v0.z + v1.z + v2.z) * (1.0f / 3.0f),
                   (v0.w + v1.w + v2.w) * (1.0f / 3.0f) };
#pragma unroll
    for (int j = 0; j < 4; ++j) {
        int bin = (int)(g[j] * 31.0f);
        bin = bin < 0 ? 0 : (bin > 31 ? 31 : bin);
        atomicAdd(&hist[wave][bin], 1);
    }
    __syncthreads();

    float t = 0.0f;
    if (lane < 32) {
        float pr = (float)hist[wave][lane] * (1.0f / 256.0f);
        t = -pr * log2f(pr + 1e-10f);
    }
#pragma unroll
    for (int off = 32; off; off >>= 1) t += __shfl_xor(t, off);
    if (lane == 0) ent[p] = t * (1.0f / 5.0f);   // / log2(32)
}

// ------- kernel 2: LDS-free direct-load bf16 MFMA GEMM + bias ---------------
// 196 blocks x 6 waves. Wave w: rows [rowBase,rowBase+64) x cols [w*64,w*64+64).
// The 16x16x32 operand fragment for lane (quad,cl) is the contiguous 16B at
// row (i*16+cl), k = ko + quad*8 — loaded straight from global (L2/L3-hot;
// the 6 waves share identical A addresses -> L1 hits). No LDS, no barriers.
// K-loop: outer 6 x inner-unroll 4 => at most 32 loads in flight per wave
// (vmcnt is 6-bit / 63 max; R6's 192-deep fully-unrolled version diverged on
// warm replays — bounding the in-flight window is the fix under test).
__global__ __launch_bounds__(384) void gemm_kernel(const unsigned short* __restrict__ A,
                                                   const unsigned short* __restrict__ Bt,
                                                   const float* __restrict__ bias,
                                                   float* __restrict__ C) {
    const int tid  = threadIdx.x;
    const int lane = tid & 63;
    const int w    = tid >> 6;                // wave 0..5
    const int quad = lane >> 4;
    const int cl   = lane & 15;
    const int rowBase = blockIdx.x * 64;

    const unsigned short* arow[4];
    const unsigned short* brow[4];
#pragma unroll
    for (int i = 0; i < 4; ++i) {
        arow[i] = A  + (size_t)(rowBase + i * 16 + cl) * KDIM + quad * 8;
        brow[i] = Bt + (size_t)(w * 64  + i * 16 + cl) * KDIM + quad * 8;
    }

    f32x4 acc[4][4] = {};
    for (int kb = 0; kb < 6; ++kb) {          // NOT unrolled: bounds code size
#pragma unroll
        for (int ku = 0; ku < 4; ++ku) {      // 32 loads, 64 MFMAs per kb
            const int ko = kb * 128 + ku * 32;
            s16x8 a_frag[4], b_frag[4];
#pragma unroll
            for (int i = 0; i < 4; ++i) {
                a_frag[i] = *(const s16x8*)(arow[i] + ko);
                b_frag[i] = *(const s16x8*)(brow[i] + ko);
            }
#pragma unroll
            for (int i = 0; i < 4; ++i)
#pragma unroll
                for (int j = 0; j < 4; ++j)
                    acc[i][j] = __builtin_amdgcn_mfma_f32_16x16x32_bf16(
                        a_frag[i], b_frag[j], acc[i][j], 0, 0, 0);
        }
    }

    // epilogue: C/D layout col = lane&15, row = (lane>>4)*4 + reg; bias only
#pragma unroll
    for (int j = 0; j < 4; ++j) {
        int col = w * 64 + j * 16 + cl;
        float bv = bias[col];
#pragma unroll
        for (int i = 0; i < 4; ++i) {
            int row0 = rowBase + i * 16 + quad * 4;
#pragma unroll
            for (int r = 0; r < 4; ++r)
                C[(size_t)(row0 + r) * DDIM + col] = acc[i][j][r] + bv;
        }
    }
}

// ---------------- kernel 3: LayerNorm (in-place on d_out x-region) -----------
__global__ __launch_bounds__(256) void ln_kernel(float* __restrict__ X,
                                                 const float* __restrict__ gamma,
                                                 const float* __restrict__ beta) {
    __shared__ float sg[DDIM], sb[DDIM];
    for (int i = threadIdx.x; i < DDIM; i += 256) { sg[i] = gamma[i]; sb[i] = beta[i]; }
    __syncthreads();
    const int lane = threadIdx.x & 63;
    const int wave = threadIdx.x >> 6;
    const int row = blockIdx.x * 4 + wave;
    float* x = X + (size_t)row * DDIM + lane * 6;

    float2 p0 = *(float2*)(x);
    float2 p1 = *(float2*)(x + 2);
    float2 p2 = *(float2*)(x + 4);
    float v[6] = { p0.x, p0.y, p1.x, p1.y, p2.x, p2.y };

    float s = v[0] + v[1] + v[2] + v[3] + v[4] + v[5];
#pragma unroll
    for (int off = 32; off; off >>= 1) s += __shfl_xor(s, off);
    float mean = s * (1.0f / (float)DDIM);

    float d = 0.0f;
#pragma unroll
    for (int j = 0; j < 6; ++j) { float t = v[j] - mean; d += t * t; }
#pragma unroll
    for (int off = 32; off; off >>= 1) d += __shfl_xor(d, off);
    float rstd = 1.0f / sqrtf(d * (1.0f / (float)DDIM) + 1e-5f);

    const float* g = sg + lane * 6;
    const float* b = sb + lane * 6;
#pragma unroll
    for (int j = 0; j < 6; ++j) x[j] = (v[j] - mean) * rstd * g[j] + b[j];
}

extern "C" void kernel_launch(void* const* d_in, const int* in_sizes, int n_in,
                              void* d_out, int out_size, void* d_ws, size_t ws_size,
                              hipStream_t stream) {
    const float* img = (const float*)d_in[0];
    const float* pw  = (const float*)d_in[1];
    const float* pb  = (const float*)d_in[2];
    const float* gam = (const float*)d_in[3];
    const float* bet = (const float*)d_in[4];
    float* out = (float*)d_out;

    unsigned short* Abf = (unsigned short*)d_ws;                       // 12544*768*2 = 19267584 B
    unsigned short* Wbf = (unsigned short*)((char*)d_ws + 19267584);   // 384*768*2  = 589824 B
    float* ent = out + (size_t)M_ROWS * DDIM;                          // entropy after x

    hipLaunchKernelGGL(patch_kernel, dim3(3424), dim3(256), 0, stream,
                       img, pw, Abf, Wbf, ent);
    hipLaunchKernelGGL(gemm_kernel,  dim3(196),  dim3(384), 0, stream,
                       Abf, Wbf, pb, out);
    hipLaunchKernelGGL(ln_kernel,    dim3(3136), dim3(256), 0, stream,
                       out, gam, bet);
}

// Round 8
// 117.797 us; speedup vs baseline: 1.1983x; 1.1983x over previous
//
#include <hip/hip_runtime.h>

// Problem constants
#define NPATCH 196
#define M_ROWS 12544          // 64*196 = 98 blocks * 128 rows
#define KDIM 768              // 3*16*16
#define DDIM 384              // EMBED
#define HW (224*224)

typedef __attribute__((ext_vector_type(8))) short s16x8;
typedef __attribute__((ext_vector_type(4))) float f32x4;
typedef __attribute__((ext_vector_type(4))) unsigned short u16x4;

__device__ __forceinline__ unsigned short f2bf(float f) {
    unsigned int u = __float_as_uint(f);
    u += 0x7fff + ((u >> 16) & 1);   // round-to-nearest-even
    return (unsigned short)(u >> 16);
}

__device__ __forceinline__ void load_lds16(const void* g, void* l) {
    __builtin_amdgcn_global_load_lds(
        (const __attribute__((address_space(1))) unsigned int*)g,
        (__attribute__((address_space(3))) unsigned int*)l, 16, 0, 0);
}

// ------- kernel 1: fused im2col(bf16) + patch entropy + weight cast ----------
// blocks [0,3136): one wave per patch -> bf16 A row + grayscale histogram.
// blocks [3136,3424): weight fp32->bf16 cast (384x768 row-major = B^T).
// (unchanged, validated R3-R7)
__global__ __launch_bounds__(256) void patch_kernel(const float* __restrict__ img,
                                                    const float* __restrict__ w,
                                                    unsigned short* __restrict__ A,
                                                    unsigned short* __restrict__ W,
                                                    float* __restrict__ ent) {
    if (blockIdx.x >= 3136) {                 // ---- weight cast part ----
        int t = (blockIdx.x - 3136) * 256 + threadIdx.x;   // 73728 float4s
        float4 v = ((const float4*)w)[t];
        u16x4 o = { f2bf(v.x), f2bf(v.y), f2bf(v.z), f2bf(v.w) };
        *(u16x4*)(W + t * 4) = o;
        return;
    }
    __shared__ int hist[4][32];
    const int lane = threadIdx.x & 63;
    const int wave = threadIdx.x >> 6;
    const int p = blockIdx.x * 4 + wave;      // 0..12543 == A row index
    const int b = p / NPATCH;
    const int n = p - b * NPATCH;
    const int ph = n / 14, pw = n - ph * 14;

    if (lane < 32) hist[wave][lane] = 0;
    __syncthreads();

    const int r = lane >> 2;                  // pixel row in patch 0..15
    const int cc = (lane & 3) * 4;            // pixel col 0,4,8,12
    const float* base = img + (size_t)b * (3 * HW) + (ph * 16 + r) * 224 + pw * 16 + cc;

    float4 v0 = *(const float4*)(base);
    float4 v1 = *(const float4*)(base + HW);
    float4 v2 = *(const float4*)(base + 2 * HW);

    unsigned short* arow = A + (size_t)p * KDIM;
    u16x4 o0 = { f2bf(v0.x), f2bf(v0.y), f2bf(v0.z), f2bf(v0.w) };
    u16x4 o1 = { f2bf(v1.x), f2bf(v1.y), f2bf(v1.z), f2bf(v1.w) };
    u16x4 o2 = { f2bf(v2.x), f2bf(v2.y), f2bf(v2.z), f2bf(v2.w) };
    *(u16x4*)(arow + 0 * 256 + lane * 4) = o0;
    *(u16x4*)(arow + 1 * 256 + lane * 4) = o1;
    *(u16x4*)(arow + 2 * 256 + lane * 4) = o2;

    float g[4] = { (v0.x + v1.x + v2.x) * (1.0f / 3.0f),
                   (v0.y + v1.y + v2.y) * (1.0f / 3.0f),
                   (v0.z + v1.z + v2.z) * (1.0f / 3.0f),
                   (v0.w + v1.w + v2.w) * (1.0f / 3.0f) };
#pragma unroll
    for (int j = 0; j < 4; ++j) {
        int bin = (int)(g[j] * 31.0f);
        bin = bin < 0 ? 0 : (bin > 31 ? 31 : bin);
        atomicAdd(&hist[wave][bin], 1);
    }
    __syncthreads();

    float t = 0.0f;
    if (lane < 32) {
        float pr = (float)hist[wave][lane] * (1.0f / 256.0f);
        t = -pr * log2f(pr + 1e-10f);
    }
#pragma unroll
    for (int off = 32; off; off >>= 1) t += __shfl_xor(t, off);
    if (lane == 0) ent[p] = t * (1.0f / 5.0f);   // / log2(32)
}

// ------- kernel 2: bf16 MFMA GEMM (128 rows x full 384 cols) + bias + LN -----
// 98 blocks x 768 threads (12 waves = 3/SIMD, m97's resident-wave count).
// Wave w: row-half wr=w&1 (64 rows), col-group wc=w>>1 (64 cols); 4x4 acc of
// 16x16x32 MFMAs; per-iter per-wave 16 ds_read_b128 : 32 MFMA (m97 ratio).
// vs R3 (Tm=64): B staging halved (58 MB total, L2-hot), waves/block doubled.
// XOR-swizzled LDS (R3/R5-proven): row r slot ks holds global chunk ks^(r&7);
// read of chunk kc uses slot kc^(cl&7) -> 2 lanes/bank (free, m136).
__global__ __launch_bounds__(768) void gemm_ln_kernel(const unsigned short* __restrict__ A,
                                                      const unsigned short* __restrict__ Bt,
                                                      const float* __restrict__ bias,
                                                      const float* __restrict__ gamma,
                                                      const float* __restrict__ beta,
                                                      float* __restrict__ C) {
    __shared__ __align__(16) unsigned short SH[(128 + 384) * 64];  // As | Bs, 64 KB
    __shared__ float sred[128], sred2[128], smean[128], srstd[128];
    unsigned short* As = SH;
    unsigned short* Bs = SH + 128 * 64;

    const int tid  = threadIdx.x;
    const int lane = tid & 63;
    const int w    = tid >> 6;                // wave 0..11
    const int wr   = w & 1;                   // row half
    const int wc   = w >> 1;                  // col group 0..5
    const int quad = lane >> 4;
    const int cl   = lane & 15;
    const int rowBase = blockIdx.x * 128;

    if (tid < 128) { sred[tid] = 0.0f; sred2[tid] = 0.0f; }

    f32x4 acc[4][4] = {};

    for (int kt = 0; kt < KDIM; kt += 64) {
        // ---- stage A tile (128x64): 1024 16B-chunks ----
        {
            int c = tid;                      // 0..767
            int r = c >> 3, ks = c & 7;
            load_lds16(A + (size_t)(rowBase + r) * KDIM + kt + ((ks ^ (r & 7)) * 8),
                       (unsigned short*)As + c * 8);
            if (tid < 256) {                  // waves 0..3: chunks 768..1023
                int c2 = 768 + tid;
                int r2 = c2 >> 3, ks2 = c2 & 7;
                load_lds16(A + (size_t)(rowBase + r2) * KDIM + kt + ((ks2 ^ (r2 & 7)) * 8),
                           (unsigned short*)As + c2 * 8);
            }
        }
        // ---- stage B tile (384x64): 3072 16B-chunks ----
#pragma unroll
        for (int i = 0; i < 4; ++i) {
            int c = i * 768 + tid;
            int n = c >> 3, ks = c & 7;
            load_lds16(Bt + (size_t)n * KDIM + kt + ((ks ^ (n & 7)) * 8),
                       (unsigned short*)Bs + c * 8);
        }
        __syncthreads();
        // ---- MFMA: 2 k-steps x 4x4 per wave ----
#pragma unroll
        for (int ks = 0; ks < 2; ++ks) {
            const int sw = (ks * 4 + quad) ^ (cl & 7);
            s16x8 a_frag[4], b_frag[4];
#pragma unroll
            for (int i = 0; i < 4; ++i) {
                a_frag[i] = *(const s16x8*)(As + (wr * 64 + i * 16 + cl) * 64 + sw * 8);
                b_frag[i] = *(const s16x8*)(Bs + (wc * 64 + i * 16 + cl) * 64 + sw * 8);
            }
#pragma unroll
            for (int i = 0; i < 4; ++i)
#pragma unroll
                for (int j = 0; j < 4; ++j)
                    acc[i][j] = __builtin_amdgcn_mfma_f32_16x16x32_bf16(
                        a_frag[i], b_frag[j], acc[i][j], 0, 0, 0);
        }
        __syncthreads();
    }

    // ---- epilogue: bias + LayerNorm(384) + write (R3-validated, 128 rows) ----
    float bv[4], gv[4], btv[4];
#pragma unroll
    for (int j = 0; j < 4; ++j) {
        int col = wc * 64 + j * 16 + cl;
        bv[j] = bias[col]; gv[j] = gamma[col]; btv[j] = beta[col];
    }
#pragma unroll
    for (int i = 0; i < 4; ++i) {
#pragma unroll
        for (int r = 0; r < 4; ++r) {
            float s1 = 0.0f, s2 = 0.0f;
#pragma unroll
            for (int j = 0; j < 4; ++j) {
                float v = acc[i][j][r] + bv[j];
                s1 += v; s2 += v * v;
            }
#pragma unroll
            for (int off = 1; off < 16; off <<= 1) {
                s1 += __shfl_xor(s1, off);
                s2 += __shfl_xor(s2, off);
            }
            if (cl == 0) {
                int row = wr * 64 + i * 16 + quad * 4 + r;
                atomicAdd(&sred[row], s1);
                atomicAdd(&sred2[row], s2);
            }
        }
    }
    __syncthreads();
    if (tid < 128) {
        float mu  = sred[tid] * (1.0f / (float)DDIM);
        float var = sred2[tid] * (1.0f / (float)DDIM) - mu * mu;
        smean[tid] = mu;
        srstd[tid] = rsqrtf(var + 1e-5f);
    }
    __syncthreads();

#pragma unroll
    for (int i = 0; i < 4; ++i) {
#pragma unroll
        for (int r = 0; r < 4; ++r) {
            int row = wr * 64 + i * 16 + quad * 4 + r;
            float mu = smean[row], rs = srstd[row];
            float* crow = C + (size_t)(rowBase + row) * DDIM;
#pragma unroll
            for (int j = 0; j < 4; ++j)
                crow[wc * 64 + j * 16 + cl] = (acc[i][j][r] + bv[j] - mu) * rs * gv[j] + btv[j];
        }
    }
}

extern "C" void kernel_launch(void* const* d_in, const int* in_sizes, int n_in,
                              void* d_out, int out_size, void* d_ws, size_t ws_size,
                              hipStream_t stream) {
    const float* img = (const float*)d_in[0];
    const float* pw  = (const float*)d_in[1];
    const float* pb  = (const float*)d_in[2];
    const float* gam = (const float*)d_in[3];
    const float* bet = (const float*)d_in[4];
    float* out = (float*)d_out;

    unsigned short* Abf = (unsigned short*)d_ws;                       // 12544*768*2 = 19267584 B
    unsigned short* Wbf = (unsigned short*)((char*)d_ws + 19267584);   // 384*768*2  = 589824 B
    float* ent = out + (size_t)M_ROWS * DDIM;                          // entropy after x

    hipLaunchKernelGGL(patch_kernel,   dim3(3424), dim3(256), 0, stream,
                       img, pw, Abf, Wbf, ent);
    hipLaunchKernelGGL(gemm_ln_kernel, dim3(98),   dim3(768), 0, stream,
                       Abf, Wbf, pb, gam, bet, out);
}